// Round 8
// baseline (400.576 us; speedup 1.0000x reference)
//
#include <hip/hip_runtime.h>
#include <math.h>

#define H      1024
#define INNER  2048
#define NST    16
#define SEQ    1024
#define ROWS   2048          // BATCH*SEQ
#define XZW    (2*INNER)     // 4096

typedef unsigned short u16;
typedef short bf16x8 __attribute__((ext_vector_type(8)));
typedef float f32x4 __attribute__((ext_vector_type(4)));

__device__ __forceinline__ u16 f2bf(float f) {
  unsigned u = __float_as_uint(f);
  return (u16)((u + 0x7FFF + ((u >> 16) & 1)) >> 16);  // RN-even
}
__device__ __forceinline__ float bf2f(u16 s) {
  return __uint_as_float(((unsigned)s) << 16);
}
__device__ __forceinline__ void gload16(const u16* g, u16* l) {
  __builtin_amdgcn_global_load_lds(
      (const __attribute__((address_space(1))) void*)g,
      (__attribute__((address_space(3))) void*)l, 16, 0, 0);
}

// ---------------- LayerNorm -> bf16 hi/lo ----------------
__global__ __launch_bounds__(256) void ln_kernel(
    const float* __restrict__ x, const float* __restrict__ w,
    const float* __restrict__ b, u16* __restrict__ ahi, u16* __restrict__ alo) {
  int row = blockIdx.x;
  int tid = threadIdx.x;
  const float4* xr = reinterpret_cast<const float4*>(x + (size_t)row * H);
  float4 v = xr[tid];
  float s = v.x + v.y + v.z + v.w;
  for (int o = 32; o > 0; o >>= 1) s += __shfl_down(s, o);
  __shared__ float r1[4], r2[4];
  int wv = tid >> 6;
  if ((tid & 63) == 0) r1[wv] = s;
  __syncthreads();
  float mu = (r1[0] + r1[1] + r1[2] + r1[3]) * (1.0f / H);
  float4 d;
  d.x = v.x - mu; d.y = v.y - mu; d.z = v.z - mu; d.w = v.w - mu;
  float sq = d.x*d.x + d.y*d.y + d.z*d.z + d.w*d.w;
  for (int o = 32; o > 0; o >>= 1) sq += __shfl_down(sq, o);
  if ((tid & 63) == 0) r2[wv] = sq;
  __syncthreads();
  float var = (r2[0] + r2[1] + r2[2] + r2[3]) * (1.0f / H);
  float rs = 1.0f / sqrtf(var + 1e-5f);
  float4 w4 = reinterpret_cast<const float4*>(w)[tid];
  float4 b4 = reinterpret_cast<const float4*>(b)[tid];
  float o0 = d.x * rs * w4.x + b4.x;
  float o1 = d.y * rs * w4.y + b4.y;
  float o2 = d.z * rs * w4.z + b4.z;
  float o3 = d.w * rs * w4.w + b4.w;
  ushort4 hh, ll;
  hh.x = f2bf(o0); ll.x = f2bf(o0 - bf2f(hh.x));
  hh.y = f2bf(o1); ll.y = f2bf(o1 - bf2f(hh.y));
  hh.z = f2bf(o2); ll.z = f2bf(o2 - bf2f(hh.z));
  hh.w = f2bf(o3); ll.w = f2bf(o3 - bf2f(hh.w));
  reinterpret_cast<ushort4*>(ahi + (size_t)row * H)[tid] = hh;
  reinterpret_cast<ushort4*>(alo + (size_t)row * H)[tid] = ll;
}

// ---------------- transpose + split weights: W[K][N] -> T{hi,lo}[N][Kout] ---------
__global__ __launch_bounds__(256) void cvt_t_kernel(
    const float* __restrict__ W, u16* __restrict__ Thi, u16* __restrict__ Tlo,
    int K, int N) {
  __shared__ float t[32][33];
  int tx = threadIdx.x & 31, ty = threadIdx.x >> 5;  // ty 0..7
  int k0 = blockIdx.y * 32, n0 = blockIdx.x * 32;
#pragma unroll
  for (int r = 0; r < 4; ++r)
    t[ty + r * 8][tx] = W[(size_t)(k0 + ty + r * 8) * N + n0 + tx];
  __syncthreads();
#pragma unroll
  for (int r = 0; r < 4; ++r) {
    int row = ty + r * 8;                 // local n
    float v = t[tx][row];
    u16 h = f2bf(v);
    size_t idx = (size_t)(n0 + row) * K + k0 + tx;
    Thi[idx] = h;
    Tlo[idx] = f2bf(v - bf2f(h));
  }
}

// ---------------- split-bf16 MFMA GEMM, dbuf + counted-vmcnt pipeline ------------
// MODE 0: C[M,N] = A@B + bias.  MODE 1: partial store (no atomics, no bias):
//   C[z*Mtot*N + m*N + n] = partial over K-range [z*Ksub, (z+1)*Ksub).
// A{hi,lo}[M][Kstride], Bt{hi,lo}[N][Kstride] bf16 hi/lo split (3-product).
template <int BN_, int MODE>
__global__ __launch_bounds__(256) void gemm_mfma(
    const u16* __restrict__ a_hi, const u16* __restrict__ a_lo,
    const u16* __restrict__ b_hi, const u16* __restrict__ b_lo,
    const float* __restrict__ bias, float* __restrict__ C, int N,
    int Kstride, int Ksub, int Mtot) {
  constexpr int MN = BN_ / 32;            // b frags per wave
  constexpr int NB = BN_ / 16;            // 1KB staging chunks per B array
  constexpr int T  = 16 + 2 * NB;         // chunks per K-step
  constexpr int CH = T / 4;               // own global_load_lds per wave per K-step
  constexpr int HALF = 128 * 32 * 2 + BN_ * 32 * 2;  // u16 per buffer
  __shared__ __align__(16) u16 lds[2 * HALF];
  const int tid = threadIdx.x;
  const int lane = tid & 63;
  const int w = tid >> 6;
  const int m0 = blockIdx.y * 128;
  const int n0 = blockIdx.x * BN_;
  const int koff = blockIdx.z * Ksub;
  const int wr = (w >> 1) * 64;
  const int wc = (w & 1) * (BN_ / 2);
  const int s = lane >> 4;
  const int rl = lane & 15;
  f32x4 acc[4][MN];
#pragma unroll
  for (int m = 0; m < 4; ++m)
#pragma unroll
    for (int n = 0; n < MN; ++n)
#pragma unroll
      for (int r = 0; r < 4; ++r) acc[m][n][r] = 0.0f;

  auto stageF = [&](int buf, int k0) {
    u16* lbase = lds + buf * HALF;
    for (int c = w; c < T; c += 4) {
      const u16* gb; int cc, rg, lo;
      if (c < 8)            { gb = a_hi; cc = c;           rg = m0; lo = 0; }
      else if (c < 16)      { gb = a_lo; cc = c - 8;       rg = m0; lo = 128 * 32; }
      else if (c < 16 + NB) { gb = b_hi; cc = c - 16;      rg = n0; lo = 128 * 64; }
      else                  { gb = b_lo; cc = c - 16 - NB; rg = n0; lo = 128 * 64 + BN_ * 32; }
      int o = cc * 1024 + lane * 16;     // byte offset within tile
      int row = o >> 6;                  // tile row (64B rows)
      int k8 = ((o >> 4) & 3) ^ ((row >> 1) & 3);
      gload16(gb + (size_t)(rg + row) * Kstride + k0 + k8 * 8,
              lbase + lo + cc * 512);
    }
  };

  const int NT = Ksub / 32;
  stageF(0, koff);
  asm volatile("s_waitcnt vmcnt(0)\n\ts_barrier" ::: "memory");
  int cur = 0;
  for (int t = 0; t < NT; ++t) {
    if (t + 1 < NT) {
      stageF(cur ^ 1, koff + (t + 1) * 32);  // async; lands during NEXT iter
      if constexpr (CH == 8)
        asm volatile("s_waitcnt vmcnt(8)\n\ts_barrier" ::: "memory");
      else if constexpr (CH == 7)
        asm volatile("s_waitcnt vmcnt(7)\n\ts_barrier" ::: "memory");
      else
        asm volatile("s_waitcnt vmcnt(6)\n\ts_barrier" ::: "memory");
    } else {
      asm volatile("s_waitcnt vmcnt(0)\n\ts_barrier" ::: "memory");
    }
    const u16* lah = lds + cur * HALF;
    const u16* lal = lah + 128 * 32;
    const u16* lbh = lah + 128 * 64;
    const u16* lbl = lbh + BN_ * 32;
    bf16x8 ah[4], al[4], bh[MN], bl[MN];
#pragma unroll
    for (int m = 0; m < 4; ++m) {
      int r = wr + m * 16 + rl;
      int sw = (s ^ ((r >> 1) & 3)) * 8;
      ah[m] = *reinterpret_cast<const bf16x8*>(lah + r * 32 + sw);
      al[m] = *reinterpret_cast<const bf16x8*>(lal + r * 32 + sw);
    }
#pragma unroll
    for (int n = 0; n < MN; ++n) {
      int r = wc + n * 16 + rl;
      int sw = (s ^ ((r >> 1) & 3)) * 8;
      bh[n] = *reinterpret_cast<const bf16x8*>(lbh + r * 32 + sw);
      bl[n] = *reinterpret_cast<const bf16x8*>(lbl + r * 32 + sw);
    }
#pragma unroll
    for (int m = 0; m < 4; ++m)
#pragma unroll
      for (int n = 0; n < MN; ++n) {
        acc[m][n] = __builtin_amdgcn_mfma_f32_16x16x32_bf16(ah[m], bh[n], acc[m][n], 0, 0, 0);
        acc[m][n] = __builtin_amdgcn_mfma_f32_16x16x32_bf16(al[m], bh[n], acc[m][n], 0, 0, 0);
        acc[m][n] = __builtin_amdgcn_mfma_f32_16x16x32_bf16(ah[m], bl[n], acc[m][n], 0, 0, 0);
      }
    // closing: WAR fence — all waves done reading buf[cur] before it is restaged
    asm volatile("s_barrier" ::: "memory");
    cur ^= 1;
  }
  float* Cz = (MODE == 1) ? C + (size_t)blockIdx.z * Mtot * N : C;
#pragma unroll
  for (int n = 0; n < MN; ++n) {
    int col = n0 + wc + n * 16 + rl;
    float bv = (MODE == 0) ? bias[col] : 0.0f;
#pragma unroll
    for (int m = 0; m < 4; ++m) {
      int r0 = m0 + wr + m * 16 + s * 4;  // C/D: col=lane&15, row=(lane>>4)*4+reg
#pragma unroll
      for (int r = 0; r < 4; ++r)
        Cz[(size_t)(r0 + r) * N + col] = acc[m][n][r] + bv;
    }
  }
}

// ---------------- GEMM3 partial reduce: d_out = bias + sum of 4 partials ----------
__global__ __launch_bounds__(256) void red3_kernel(
    const float* __restrict__ p, const float* __restrict__ out_b,
    float* __restrict__ out) {
  int i = (blockIdx.x * 256 + threadIdx.x) * 4;   // over 2048*1024
  float4 a = *reinterpret_cast<const float4*>(p + i);
  float4 b = *reinterpret_cast<const float4*>(p + 2097152 + i);
  float4 c = *reinterpret_cast<const float4*>(p + 2 * 2097152 + i);
  float4 d = *reinterpret_cast<const float4*>(p + 3 * 2097152 + i);
  float4 bb = *reinterpret_cast<const float4*>(out_b + (i & (H - 1)));
  float4 o;
  o.x = a.x + b.x + c.x + d.x + bb.x;
  o.y = a.y + b.y + c.y + d.y + bb.y;
  o.z = a.z + b.z + c.z + d.z + bb.z;
  o.w = a.w + b.w + c.w + d.w + bb.w;
  *reinterpret_cast<float4*>(out + i) = o;
}

// ---------------- bcdtr partial reduce: bcd = bias + sum of 16 partials -----------
__global__ __launch_bounds__(256) void redb_kernel(
    const float* __restrict__ p, const float* __restrict__ bc_b,
    const float* __restrict__ dtr_b, float* __restrict__ bcd) {
  int i = blockIdx.x * 256 + threadIdx.x;          // over 2048*96
  int col = i % 96;
  float s = (col < 32) ? bc_b[col] : dtr_b[col - 32];
#pragma unroll
  for (int k = 0; k < 16; ++k) s += p[(size_t)k * (ROWS * 96) + i];
  bcd[i] = s;
}

// ---------------- causal conv (width 4) + SiLU -> f32 + bf16 hi/lo ----------------
__global__ __launch_bounds__(256) void conv_kernel(
    const float* __restrict__ xz, const float* __restrict__ cw,
    const float* __restrict__ cb, float* __restrict__ xa,
    u16* __restrict__ xahi, u16* __restrict__ xalo) {
  int row = blockIdx.x;
  int t = row & (SEQ - 1);
  int tid = threadIdx.x;
  for (int d = tid; d < INNER; d += 256) {
    float4 w = reinterpret_cast<const float4*>(cw)[d];
    float wj[4] = {w.x, w.y, w.z, w.w};
    float acc = cb[d];
#pragma unroll
    for (int j = 0; j < 4; ++j) {
      int ts = t - 3 + j;
      if (ts >= 0) acc = fmaf(xz[(size_t)(row - 3 + j) * XZW + d], wj[j], acc);
    }
    float sv = acc / (1.0f + __expf(-acc));
    size_t idx = (size_t)row * INNER + d;
    xa[idx] = sv;
    u16 hh = f2bf(sv);
    xahi[idx] = hh;
    xalo[idx] = f2bf(sv - bf2f(hh));
  }
}

// ---------------- dt = clip(softplus(dtr @ dt_w + dt_b)) + row mean + scanBC ------
__global__ __launch_bounds__(256) void dtsp_kernel(
    const float* __restrict__ bcd, const float* __restrict__ dt_w,
    const float* __restrict__ dt_b, float* __restrict__ dt,
    float* __restrict__ dtm, float* __restrict__ scanBC) {
  int tid = threadIdx.x;
  int row0 = blockIdx.x * 8;
  __shared__ float rl[8][64];
  __shared__ float psum[8][4];
  __shared__ float dtmrow[8];
  for (int i = tid; i < 512; i += 256)
    rl[i >> 6][i & 63] = bcd[(size_t)(row0 + (i >> 6)) * 96 + 32 + (i & 63)];
  __syncthreads();
  float lsum[8] = {};
  for (int j = 0; j < 8; ++j) {
    int d = tid + j * 256;
    float acc[8];
    float bb = dt_b[d];
#pragma unroll
    for (int r = 0; r < 8; ++r) acc[r] = bb;
#pragma unroll 8
    for (int k = 0; k < 64; ++k) {
      float w = dt_w[(size_t)k * INNER + d];
#pragma unroll
      for (int r = 0; r < 8; ++r) acc[r] = fmaf(rl[r][k], w, acc[r]);
    }
#pragma unroll
    for (int r = 0; r < 8; ++r) {
      float xv = acc[r];
      float sp = (xv > 15.0f) ? xv : log1pf(__expf(xv));
      float dv = fminf(fmaxf(sp, 1e-3f), 0.1f);
      dt[(size_t)(row0 + r) * INNER + d] = dv;
      lsum[r] += dv;
    }
  }
#pragma unroll
  for (int r = 0; r < 8; ++r) {
    float s = lsum[r];
    for (int o = 32; o > 0; o >>= 1) s += __shfl_down(s, o);
    if ((tid & 63) == 0) psum[r][tid >> 6] = s;
  }
  __syncthreads();
  if (tid < 8) {
    float v =
        (psum[tid][0] + psum[tid][1] + psum[tid][2] + psum[tid][3]) * (1.0f / INNER);
    dtm[row0 + tid] = v;
    dtmrow[tid] = v;
  }
  __syncthreads();
  // fused dmb: scanBC[row][32] = {dtm*B[16], C[16]}
  int rr = tid >> 5, cc = tid & 31;
  float v = bcd[(size_t)(row0 + rr) * 96 + cc];
  if (cc < 16) v *= dtmrow[rr];
  scanBC[(size_t)(row0 + rr) * 32 + cc] = v;
}

// ---------------- chunked scan: phase 1 (chunk-local scan + decay product) --------
__global__ __launch_bounds__(256) void scan1_kernel(
    const float* __restrict__ dt, const float* __restrict__ xa,
    const float* __restrict__ scanBC, float* __restrict__ Abuf,
    float* __restrict__ hbuf, int NC, int CL) {
  int tid = threadIdx.x;
  int dl = tid & 63;
  int NCB = NC >> 2;
  int bi = blockIdx.x;
  int cg = bi % NCB;
  int dg = (bi / NCB) & 31;
  int b = bi / (NCB * 32);
  int d = dg * 64 + dl;
  int c = cg * 4 + (tid >> 6);
  size_t r = (size_t)b * SEQ + (size_t)c * CL;
  const float* dtp = dt + r * INNER + d;
  const float* xap = xa + r * INNER + d;
  const float* bcp = scanBC + r * 32;
  float h[16];
#pragma unroll
  for (int n = 0; n < 16; ++n) h[n] = 0.0f;
  float S = 0.0f;
#pragma unroll 2
  for (int t = 0; t < CL; ++t) {
    float dtv = dtp[0];
    float xav = xap[0];
    float bB[16];
#pragma unroll
    for (int q = 0; q < 4; ++q)
      *reinterpret_cast<float4*>(&bB[q * 4]) =
          *reinterpret_cast<const float4*>(bcp + q * 4);
    S += dtv;
    float e1 = __expf(-dtv);
    float w = e1;
#pragma unroll
    for (int n = 0; n < 16; ++n) {
      h[n] = fmaf(w, h[n], xav * bB[n]);
      w *= e1;
    }
    dtp += INNER;
    xap += INNER;
    bcp += 32;
  }
  size_t base = (((size_t)b * NC + c) * INNER + d) * 16;
  float eS = __expf(-S);
  float A[16];
  float w = eS;
#pragma unroll
  for (int n = 0; n < 16; ++n) { A[n] = w; w *= eS; }
#pragma unroll
  for (int q = 0; q < 4; ++q) {
    *reinterpret_cast<float4*>(Abuf + base + q * 4) =
        *reinterpret_cast<float4*>(&A[q * 4]);
    *reinterpret_cast<float4*>(hbuf + base + q * 4) =
        *reinterpret_cast<float4*>(&h[q * 4]);
  }
}

// ---------------- chunked scan: phase 2 (cross-chunk fixup; hbuf -> h_in) --------
__global__ __launch_bounds__(256) void scan2_kernel(
    const float* __restrict__ Abuf, float* __restrict__ hbuf, int NC) {
  int idx = blockIdx.x * 256 + threadIdx.x;
  size_t stride = (size_t)INNER * 16;
  size_t base = (size_t)(idx >> 15) * NC * stride + (size_t)(idx & 32767);
  float h = 0.0f;
  for (int c = 0; c < NC; ++c) {
    float A = Abuf[base];
    float hl = hbuf[base];
    hbuf[base] = h;
    h = fmaf(A, h, hl);
    base += stride;
  }
}

// ---------------- chunked scan: phase 3 (replay + y + gating -> bf16 hi/lo) -------
__global__ __launch_bounds__(256) void scan3_kernel(
    const float* __restrict__ dt, const float* __restrict__ xa,
    const float* __restrict__ scanBC, const float* __restrict__ xz,
    const float* __restrict__ hbuf, u16* __restrict__ ghi, u16* __restrict__ glo,
    int NC, int CL) {
  int tid = threadIdx.x;
  int dl = tid & 63;
  int NCB = NC >> 2;
  int bi = blockIdx.x;
  int cg = bi % NCB;
  int dg = (bi / NCB) & 31;
  int b = bi / (NCB * 32);
  int d = dg * 64 + dl;
  int c = cg * 4 + (tid >> 6);
  size_t r = (size_t)b * SEQ + (size_t)c * CL;
  const float* dtp = dt + r * INNER + d;
  const float* xap = xa + r * INNER + d;
  const float* bcp = scanBC + r * 32;
  const float* zp = xz + r * XZW + INNER + d;
  u16* ghp = ghi + r * INNER + d;
  u16* glp = glo + r * INNER + d;
  size_t hb = (((size_t)b * NC + c) * INNER + d) * 16;
  float h[16];
#pragma unroll
  for (int q = 0; q < 4; ++q)
    *reinterpret_cast<float4*>(&h[q * 4]) =
        *reinterpret_cast<const float4*>(hbuf + hb + q * 4);
#pragma unroll 2
  for (int t = 0; t < CL; ++t) {
    float dtv = dtp[0];
    float xav = xap[0];
    float zv = zp[0];
    float bB[16], cC[16];
#pragma unroll
    for (int q = 0; q < 4; ++q) {
      *reinterpret_cast<float4*>(&bB[q * 4]) =
          *reinterpret_cast<const float4*>(bcp + q * 4);
      *reinterpret_cast<float4*>(&cC[q * 4]) =
          *reinterpret_cast<const float4*>(bcp + 16 + q * 4);
    }
    float e1 = __expf(-dtv);
    float w = e1;
    float y = 0.0f;
#pragma unroll
    for (int n = 0; n < 16; ++n) {
      h[n] = fmaf(w, h[n], xav * bB[n]);
      w *= e1;
      y = fmaf(h[n], cC[n], y);
    }
    float sz = zv / (1.0f + __expf(-zv));
    float g = y * sz;
    u16 gh = f2bf(g);
    ghp[0] = gh;
    glp[0] = f2bf(g - bf2f(gh));
    dtp += INNER;
    xap += INNER;
    bcp += 32;
    zp += XZW;
    ghp += INNER;
    glp += INNER;
  }
}

extern "C" void kernel_launch(void* const* d_in, const int* in_sizes, int n_in,
                              void* d_out, int out_size, void* d_ws, size_t ws_size,
                              hipStream_t stream) {
  const float* x      = (const float*)d_in[0];
  const float* norm_w = (const float*)d_in[1];
  const float* norm_b = (const float*)d_in[2];
  const float* in_w   = (const float*)d_in[3];
  const float* in_b   = (const float*)d_in[4];
  const float* conv_w = (const float*)d_in[5];
  const float* conv_b = (const float*)d_in[6];
  const float* bc_w   = (const float*)d_in[7];
  const float* bc_b   = (const float*)d_in[8];
  const float* dtr_w  = (const float*)d_in[9];
  const float* dtr_b  = (const float*)d_in[10];
  const float* dt_w   = (const float*)d_in[11];
  const float* dt_b   = (const float*)d_in[12];
  const float* out_w  = (const float*)d_in[13];
  const float* out_b  = (const float*)d_in[14];

  float* ws = (float*)d_ws;
  float* xz     = ws;                   // 8,388,608 (dead after scan3 -> part3)
  float* xa     = ws + 8388608;         // 4,194,304
  float* bcd    = ws + 12582912;        // 196,608
  float* dt     = ws + 12779520;        // 4,194,304
  float* dtm    = ws + 16973824;        // 2,048
  float* scanBC = ws + 16975872;        // 65,536
  // region R @ 17,041,408 (6,291,456 floats), time-multiplexed:
  u16* a1hi   = (u16*)(ws + 17041408);  // 2048*1024 u16
  u16* a1lo   = (u16*)(ws + 18089984);
  u16* b1thi  = (u16*)(ws + 19138560);  // 4096*1024 u16
  u16* b1tlo  = (u16*)(ws + 21235712);
  u16* xahi   = (u16*)(ws + 17041408);  // 2048*2048 u16
  u16* xalo   = (u16*)(ws + 19138560);
  u16* bcdThi = (u16*)(ws + 21235712);  // 96*2048 u16
  u16* bcdTlo = (u16*)(ws + 21334016);
  u16* g3hi   = (u16*)(ws + 17041408);  // 2048*2048 u16
  u16* g3lo   = (u16*)(ws + 19138560);
  u16* b3thi  = (u16*)(ws + 21235712);  // 1024*2048 u16
  u16* b3tlo  = (u16*)(ws + 22284288);
  float* Abuf = ws + 23332864;          // NC*65,536 (bcdtr partials before scan1)
  const int NC = 64, CL = SEQ / NC;
  float* hbuf = Abuf + (size_t)NC * 65536;  // end: 31,721,472 floats = 126.9 MB
  float* partb = Abuf;                  // 16*2048*96 = 3,145,728 <= 4,194,304 ok
  float* part3 = xz;                    // 4*2048*1024 = 8,388,608 == xz size ok

  ln_kernel<<<ROWS, 256, 0, stream>>>(x, norm_w, norm_b, a1hi, a1lo);
  cvt_t_kernel<<<dim3(XZW / 32, H / 32), 256, 0, stream>>>(in_w, b1thi, b1tlo, H, XZW);
  gemm_mfma<128, 0><<<dim3(XZW / 128, ROWS / 128, 1), 256, 0, stream>>>(
      a1hi, a1lo, b1thi, b1tlo, in_b, xz, XZW, H, H, ROWS);
  conv_kernel<<<ROWS, 256, 0, stream>>>(xz, conv_w, conv_b, xa, xahi, xalo);
  // weights -> bcdT (bc rows 0..31, dtr rows 32..95)
  cvt_t_kernel<<<dim3(1, INNER / 32), 256, 0, stream>>>(bc_w, bcdThi, bcdTlo,
                                                        INNER, 32);
  cvt_t_kernel<<<dim3(2, INNER / 32), 256, 0, stream>>>(
      dtr_w, bcdThi + 32 * 2048, bcdTlo + 32 * 2048, INNER, 64);
  // bcdtr: N=96 GEMM, split-K=16, partial stores (no atomics) + reduce
  gemm_mfma<96, 1><<<dim3(1, ROWS / 128, 16), 256, 0, stream>>>(
      xahi, xalo, bcdThi, bcdTlo, nullptr, partb, 96, INNER, INNER / 16, ROWS);
  redb_kernel<<<ROWS * 96 / 256, 256, 0, stream>>>(partb, bc_b, dtr_b, bcd);
  dtsp_kernel<<<ROWS / 8, 256, 0, stream>>>(bcd, dt_w, dt_b, dt, dtm, scanBC);
  cvt_t_kernel<<<dim3(H / 32, INNER / 32), 256, 0, stream>>>(out_w, b3thi, b3tlo,
                                                             INNER, H);
  scan1_kernel<<<2 * 32 * (NC / 4), 256, 0, stream>>>(dt, xa, scanBC, Abuf, hbuf,
                                                      NC, CL);
  scan2_kernel<<<256, 256, 0, stream>>>(Abuf, hbuf, NC);
  scan3_kernel<<<2 * 32 * (NC / 4), 256, 0, stream>>>(dt, xa, scanBC, xz, hbuf,
                                                      g3hi, g3lo, NC, CL);
  // GEMM3: split-K=4, partial stores into dead xz region + reduce w/ bias
  gemm_mfma<64, 1><<<dim3(H / 64, ROWS / 128, 4), 256, 0, stream>>>(
      g3hi, g3lo, b3thi, b3tlo, nullptr, part3, H, INNER, INNER / 4, ROWS);
  red3_kernel<<<ROWS * H / 1024, 256, 0, stream>>>(part3, out_b, (float*)d_out);
}

// Round 12
// 372.813 us; speedup vs baseline: 1.0745x; 1.0745x over previous
//
#include <hip/hip_runtime.h>
#include <math.h>

#define H      1024
#define INNER  2048
#define NST    16
#define SEQ    1024
#define ROWS   2048          // BATCH*SEQ
#define XZW    (2*INNER)     // 4096

typedef unsigned short u16;
typedef short bf16x8 __attribute__((ext_vector_type(8)));
typedef float f32x4 __attribute__((ext_vector_type(4)));

__device__ __forceinline__ u16 f2bf(float f) {
  unsigned u = __float_as_uint(f);
  return (u16)((u + 0x7FFF + ((u >> 16) & 1)) >> 16);  // RN-even
}
__device__ __forceinline__ float bf2f(u16 s) {
  return __uint_as_float(((unsigned)s) << 16);
}
__device__ __forceinline__ void gload16(const u16* g, u16* l) {
  __builtin_amdgcn_global_load_lds(
      (const __attribute__((address_space(1))) void*)g,
      (__attribute__((address_space(3))) void*)l, 16, 0, 0);
}

// ---------------- LayerNorm -> bf16 hi/lo ----------------
__global__ __launch_bounds__(256) void ln_kernel(
    const float* __restrict__ x, const float* __restrict__ w,
    const float* __restrict__ b, u16* __restrict__ ahi, u16* __restrict__ alo) {
  int row = blockIdx.x;
  int tid = threadIdx.x;
  const float4* xr = reinterpret_cast<const float4*>(x + (size_t)row * H);
  float4 v = xr[tid];
  float s = v.x + v.y + v.z + v.w;
  for (int o = 32; o > 0; o >>= 1) s += __shfl_down(s, o);
  __shared__ float r1[4], r2[4];
  int wv = tid >> 6;
  if ((tid & 63) == 0) r1[wv] = s;
  __syncthreads();
  float mu = (r1[0] + r1[1] + r1[2] + r1[3]) * (1.0f / H);
  float4 d;
  d.x = v.x - mu; d.y = v.y - mu; d.z = v.z - mu; d.w = v.w - mu;
  float sq = d.x*d.x + d.y*d.y + d.z*d.z + d.w*d.w;
  for (int o = 32; o > 0; o >>= 1) sq += __shfl_down(sq, o);
  if ((tid & 63) == 0) r2[wv] = sq;
  __syncthreads();
  float var = (r2[0] + r2[1] + r2[2] + r2[3]) * (1.0f / H);
  float rs = 1.0f / sqrtf(var + 1e-5f);
  float4 w4 = reinterpret_cast<const float4*>(w)[tid];
  float4 b4 = reinterpret_cast<const float4*>(b)[tid];
  float o0 = d.x * rs * w4.x + b4.x;
  float o1 = d.y * rs * w4.y + b4.y;
  float o2 = d.z * rs * w4.z + b4.z;
  float o3 = d.w * rs * w4.w + b4.w;
  ushort4 hh, ll;
  hh.x = f2bf(o0); ll.x = f2bf(o0 - bf2f(hh.x));
  hh.y = f2bf(o1); ll.y = f2bf(o1 - bf2f(hh.y));
  hh.z = f2bf(o2); ll.z = f2bf(o2 - bf2f(hh.z));
  hh.w = f2bf(o3); ll.w = f2bf(o3 - bf2f(hh.w));
  reinterpret_cast<ushort4*>(ahi + (size_t)row * H)[tid] = hh;
  reinterpret_cast<ushort4*>(alo + (size_t)row * H)[tid] = ll;
}

// ---------------- transpose + split weights: W[K][N] -> T{hi,lo}[N][Kout] ---------
__global__ __launch_bounds__(256) void cvt_t_kernel(
    const float* __restrict__ W, u16* __restrict__ Thi, u16* __restrict__ Tlo,
    int K, int N) {
  __shared__ float t[32][33];
  int tx = threadIdx.x & 31, ty = threadIdx.x >> 5;  // ty 0..7
  int k0 = blockIdx.y * 32, n0 = blockIdx.x * 32;
#pragma unroll
  for (int r = 0; r < 4; ++r)
    t[ty + r * 8][tx] = W[(size_t)(k0 + ty + r * 8) * N + n0 + tx];
  __syncthreads();
#pragma unroll
  for (int r = 0; r < 4; ++r) {
    int row = ty + r * 8;                 // local n
    float v = t[tx][row];
    u16 h = f2bf(v);
    size_t idx = (size_t)(n0 + row) * K + k0 + tx;
    Thi[idx] = h;
    Tlo[idx] = f2bf(v - bf2f(h));
  }
}

// ---------------- split-bf16 MFMA GEMM, dbuf + counted-vmcnt + hoisted staging ----
// C[M,N](+)= A@B (+bias if !ATOMIC). A{hi,lo}[M][Kstride], Bt{hi,lo}[N][Kstride].
// Staging addresses advance linearly in K: precompute CH {gptr, lds-off}
// descriptors ONCE (static-indexed -> registers), in-loop stage is CH bare
// global_load_lds. Kills the per-K-step 64-bit muls + branch chain (VALUBusy).
template <int BN_, bool ATOMIC>
__global__ __launch_bounds__(256) void gemm_mfma(
    const u16* __restrict__ a_hi, const u16* __restrict__ a_lo,
    const u16* __restrict__ b_hi, const u16* __restrict__ b_lo,
    const float* __restrict__ bias, float* __restrict__ C, int N,
    int Kstride, int Ksub) {
  constexpr int MN = BN_ / 32;            // b frags per wave
  constexpr int NB = BN_ / 16;            // 1KB staging chunks per B array
  constexpr int T  = 16 + 2 * NB;         // chunks per K-step
  constexpr int CH = T / 4;               // own global_load_lds per wave per K-step
  constexpr int HALF = 128 * 32 * 2 + BN_ * 32 * 2;  // u16 per buffer
  __shared__ __align__(16) u16 lds[2 * HALF];
  const int tid = threadIdx.x;
  const int lane = tid & 63;
  const int w = tid >> 6;
  const int m0 = blockIdx.y * 128;
  const int n0 = blockIdx.x * BN_;
  const int koff = blockIdx.z * Ksub;
  const int wr = (w >> 1) * 64;
  const int wc = (w & 1) * (BN_ / 2);
  const int s = lane >> 4;
  const int rl = lane & 15;
  f32x4 acc[4][MN];
#pragma unroll
  for (int m = 0; m < 4; ++m)
#pragma unroll
    for (int n = 0; n < MN; ++n)
#pragma unroll
      for (int r = 0; r < 4; ++r) acc[m][n][r] = 0.0f;

  // hoisted staging descriptors (static index -> registers, rule #20)
  const u16* gp[CH];
  int lof[CH];
#pragma unroll
  for (int i = 0; i < CH; ++i) {
    int c = w + i * 4;
    const u16* gb; int cc, rg, lo;
    if (c < 8)            { gb = a_hi; cc = c;           rg = m0; lo = 0; }
    else if (c < 16)      { gb = a_lo; cc = c - 8;       rg = m0; lo = 128 * 32; }
    else if (c < 16 + NB) { gb = b_hi; cc = c - 16;      rg = n0; lo = 128 * 64; }
    else                  { gb = b_lo; cc = c - 16 - NB; rg = n0; lo = 128 * 64 + BN_ * 32; }
    int o = cc * 1024 + lane * 16;       // byte offset within tile
    int row = o >> 6;                    // tile row (64B rows)
    int k8 = ((o >> 4) & 3) ^ ((row >> 1) & 3);
    gp[i] = gb + (size_t)(rg + row) * Kstride + koff + k8 * 8;
    lof[i] = lo + cc * 512;
  }
  auto stage = [&](int buf, int ks) {    // ks = u16 advance along K
    u16* lbase = lds + buf * HALF;
#pragma unroll
    for (int i = 0; i < CH; ++i) gload16(gp[i] + ks, lbase + lof[i]);
  };

  const int NT = Ksub / 32;
  stage(0, 0);
  asm volatile("s_waitcnt vmcnt(0)\n\ts_barrier" ::: "memory");
  int cur = 0;
  for (int t = 0; t < NT; ++t) {
    if (t + 1 < NT) {
      stage(cur ^ 1, (t + 1) * 32);      // async; lands during NEXT iter
      // opening: wait own stage(t) only (all older than the CH just issued)
      if constexpr (CH == 8)
        asm volatile("s_waitcnt vmcnt(8)\n\ts_barrier" ::: "memory");
      else if constexpr (CH == 7)
        asm volatile("s_waitcnt vmcnt(7)\n\ts_barrier" ::: "memory");
      else
        asm volatile("s_waitcnt vmcnt(6)\n\ts_barrier" ::: "memory");
    } else {
      asm volatile("s_waitcnt vmcnt(0)\n\ts_barrier" ::: "memory");
    }
    const u16* lah = lds + cur * HALF;
    const u16* lal = lah + 128 * 32;
    const u16* lbh = lah + 128 * 64;
    const u16* lbl = lbh + BN_ * 32;
    bf16x8 ah[4], al[4], bh[MN], bl[MN];
#pragma unroll
    for (int m = 0; m < 4; ++m) {
      int r = wr + m * 16 + rl;
      int sw = (s ^ ((r >> 1) & 3)) * 8;
      ah[m] = *reinterpret_cast<const bf16x8*>(lah + r * 32 + sw);
      al[m] = *reinterpret_cast<const bf16x8*>(lal + r * 32 + sw);
    }
#pragma unroll
    for (int n = 0; n < MN; ++n) {
      int r = wc + n * 16 + rl;
      int sw = (s ^ ((r >> 1) & 3)) * 8;
      bh[n] = *reinterpret_cast<const bf16x8*>(lbh + r * 32 + sw);
      bl[n] = *reinterpret_cast<const bf16x8*>(lbl + r * 32 + sw);
    }
#pragma unroll
    for (int m = 0; m < 4; ++m)
#pragma unroll
      for (int n = 0; n < MN; ++n) {
        acc[m][n] = __builtin_amdgcn_mfma_f32_16x16x32_bf16(ah[m], bh[n], acc[m][n], 0, 0, 0);
        acc[m][n] = __builtin_amdgcn_mfma_f32_16x16x32_bf16(al[m], bh[n], acc[m][n], 0, 0, 0);
        acc[m][n] = __builtin_amdgcn_mfma_f32_16x16x32_bf16(ah[m], bl[n], acc[m][n], 0, 0, 0);
      }
    // closing: WAR fence — all waves done reading buf[cur] before it is restaged
    asm volatile("s_barrier" ::: "memory");
    cur ^= 1;
  }
#pragma unroll
  for (int n = 0; n < MN; ++n) {
    int col = n0 + wc + n * 16 + rl;
    float bv = ATOMIC ? 0.0f : bias[col];
#pragma unroll
    for (int m = 0; m < 4; ++m) {
      int r0 = m0 + wr + m * 16 + s * 4;  // C/D: col=lane&15, row=(lane>>4)*4+reg
#pragma unroll
      for (int r = 0; r < 4; ++r) {
        if (ATOMIC)
          atomicAdd(&C[(size_t)(r0 + r) * N + col], acc[m][n][r]);
        else
          C[(size_t)(r0 + r) * N + col] = acc[m][n][r] + bv;
      }
    }
  }
}

// ---------------- causal conv (width 4) + SiLU -> f32 + bf16 hi/lo ----------------
__global__ __launch_bounds__(256) void conv_kernel(
    const float* __restrict__ xz, const float* __restrict__ cw,
    const float* __restrict__ cb, float* __restrict__ xa,
    u16* __restrict__ xahi, u16* __restrict__ xalo) {
  int row = blockIdx.x;
  int t = row & (SEQ - 1);
  int tid = threadIdx.x;
  for (int d = tid; d < INNER; d += 256) {
    float4 w = reinterpret_cast<const float4*>(cw)[d];
    float wj[4] = {w.x, w.y, w.z, w.w};
    float acc = cb[d];
#pragma unroll
    for (int j = 0; j < 4; ++j) {
      int ts = t - 3 + j;
      if (ts >= 0) acc = fmaf(xz[(size_t)(row - 3 + j) * XZW + d], wj[j], acc);
    }
    float sv = acc / (1.0f + __expf(-acc));
    size_t idx = (size_t)row * INNER + d;
    xa[idx] = sv;
    u16 hh = f2bf(sv);
    xahi[idx] = hh;
    xalo[idx] = f2bf(sv - bf2f(hh));
  }
}

// ---------------- bcd init: bcd[row][96] = bias (bc_b | dtr_b) ----------------
__global__ __launch_bounds__(256) void bcd_init_kernel(
    const float* __restrict__ bc_b, const float* __restrict__ dtr_b,
    float* __restrict__ bcd) {
  int i = blockIdx.x * 256 + threadIdx.x;   // 2048*96 total
  int col = i % 96;
  bcd[i] = (col < 32) ? bc_b[col] : dtr_b[col - 32];
}

// ---------------- out init: d_out[row][1024] = out_b ----------------
__global__ __launch_bounds__(256) void out_init_kernel(
    const float* __restrict__ out_b, float* __restrict__ out) {
  int i = blockIdx.x * 256 + threadIdx.x;
  out[i] = out_b[i & (H - 1)];
}

// ---------------- dt = clip(softplus(dtr @ dt_w + dt_b)) + row mean + scanBC ------
__global__ __launch_bounds__(256) void dtsp_kernel(
    const float* __restrict__ bcd, const float* __restrict__ dt_w,
    const float* __restrict__ dt_b, float* __restrict__ dt,
    float* __restrict__ dtm, float* __restrict__ scanBC) {
  int tid = threadIdx.x;
  int row0 = blockIdx.x * 8;
  __shared__ float rl[8][64];
  __shared__ float psum[8][4];
  __shared__ float dtmrow[8];
  for (int i = tid; i < 512; i += 256)
    rl[i >> 6][i & 63] = bcd[(size_t)(row0 + (i >> 6)) * 96 + 32 + (i & 63)];
  __syncthreads();
  float lsum[8] = {};
  for (int j = 0; j < 8; ++j) {
    int d = tid + j * 256;
    float acc[8];
    float bb = dt_b[d];
#pragma unroll
    for (int r = 0; r < 8; ++r) acc[r] = bb;
#pragma unroll 8
    for (int k = 0; k < 64; ++k) {
      float w = dt_w[(size_t)k * INNER + d];
#pragma unroll
      for (int r = 0; r < 8; ++r) acc[r] = fmaf(rl[r][k], w, acc[r]);
    }
#pragma unroll
    for (int r = 0; r < 8; ++r) {
      float xv = acc[r];
      float sp = (xv > 15.0f) ? xv : log1pf(__expf(xv));
      float dv = fminf(fmaxf(sp, 1e-3f), 0.1f);
      dt[(size_t)(row0 + r) * INNER + d] = dv;
      lsum[r] += dv;
    }
  }
#pragma unroll
  for (int r = 0; r < 8; ++r) {
    float s = lsum[r];
    for (int o = 32; o > 0; o >>= 1) s += __shfl_down(s, o);
    if ((tid & 63) == 0) psum[r][tid >> 6] = s;
  }
  __syncthreads();
  if (tid < 8) {
    float v =
        (psum[tid][0] + psum[tid][1] + psum[tid][2] + psum[tid][3]) * (1.0f / INNER);
    dtm[row0 + tid] = v;
    dtmrow[tid] = v;
  }
  __syncthreads();
  // fused dmb: scanBC[row][32] = {dtm*B[16], C[16]}
  int rr = tid >> 5, cc = tid & 31;
  float v = bcd[(size_t)(row0 + rr) * 96 + cc];
  if (cc < 16) v *= dtmrow[rr];
  scanBC[(size_t)(row0 + rr) * 32 + cc] = v;
}

// ---------------- chunked scan: phase 1 (chunk-local scan + decay product) --------
__global__ __launch_bounds__(256) void scan1_kernel(
    const float* __restrict__ dt, const float* __restrict__ xa,
    const float* __restrict__ scanBC, float* __restrict__ Abuf,
    float* __restrict__ hbuf, int NC, int CL) {
  int tid = threadIdx.x;
  int dl = tid & 63;
  int NCB = NC >> 2;
  int bi = blockIdx.x;
  int cg = bi % NCB;
  int dg = (bi / NCB) & 31;
  int b = bi / (NCB * 32);
  int d = dg * 64 + dl;
  int c = cg * 4 + (tid >> 6);
  size_t r = (size_t)b * SEQ + (size_t)c * CL;
  const float* dtp = dt + r * INNER + d;
  const float* xap = xa + r * INNER + d;
  const float* bcp = scanBC + r * 32;
  float h[16];
#pragma unroll
  for (int n = 0; n < 16; ++n) h[n] = 0.0f;
  float S = 0.0f;
#pragma unroll 2
  for (int t = 0; t < CL; ++t) {
    float dtv = dtp[0];
    float xav = xap[0];
    float bB[16];
#pragma unroll
    for (int q = 0; q < 4; ++q)
      *reinterpret_cast<float4*>(&bB[q * 4]) =
          *reinterpret_cast<const float4*>(bcp + q * 4);
    S += dtv;
    float e1 = __expf(-dtv);
    float w = e1;
#pragma unroll
    for (int n = 0; n < 16; ++n) {
      h[n] = fmaf(w, h[n], xav * bB[n]);
      w *= e1;
    }
    dtp += INNER;
    xap += INNER;
    bcp += 32;
  }
  size_t base = (((size_t)b * NC + c) * INNER + d) * 16;
  float eS = __expf(-S);
  float A[16];
  float w = eS;
#pragma unroll
  for (int n = 0; n < 16; ++n) { A[n] = w; w *= eS; }
#pragma unroll
  for (int q = 0; q < 4; ++q) {
    *reinterpret_cast<float4*>(Abuf + base + q * 4) =
        *reinterpret_cast<float4*>(&A[q * 4]);
    *reinterpret_cast<float4*>(hbuf + base + q * 4) =
        *reinterpret_cast<float4*>(&h[q * 4]);
  }
}

// ---------------- chunked scan: phase 2 (cross-chunk fixup; hbuf -> h_in) --------
__global__ __launch_bounds__(256) void scan2_kernel(
    const float* __restrict__ Abuf, float* __restrict__ hbuf, int NC) {
  int idx = blockIdx.x * 256 + threadIdx.x;
  size_t stride = (size_t)INNER * 16;
  size_t base = (size_t)(idx >> 15) * NC * stride + (size_t)(idx & 32767);
  float h = 0.0f;
  for (int c = 0; c < NC; ++c) {
    float A = Abuf[base];
    float hl = hbuf[base];
    hbuf[base] = h;
    h = fmaf(A, h, hl);
    base += stride;
  }
}

// ---------------- chunked scan: phase 3 (replay + y + gating -> bf16 hi/lo) -------
__global__ __launch_bounds__(256) void scan3_kernel(
    const float* __restrict__ dt, const float* __restrict__ xa,
    const float* __restrict__ scanBC, const float* __restrict__ xz,
    const float* __restrict__ hbuf, u16* __restrict__ ghi, u16* __restrict__ glo,
    int NC, int CL) {
  int tid = threadIdx.x;
  int dl = tid & 63;
  int NCB = NC >> 2;
  int bi = blockIdx.x;
  int cg = bi % NCB;
  int dg = (bi / NCB) & 31;
  int b = bi / (NCB * 32);
  int d = dg * 64 + dl;
  int c = cg * 4 + (tid >> 6);
  size_t r = (size_t)b * SEQ + (size_t)c * CL;
  const float* dtp = dt + r * INNER + d;
  const float* xap = xa + r * INNER + d;
  const float* bcp = scanBC + r * 32;
  const float* zp = xz + r * XZW + INNER + d;
  u16* ghp = ghi + r * INNER + d;
  u16* glp = glo + r * INNER + d;
  size_t hb = (((size_t)b * NC + c) * INNER + d) * 16;
  float h[16];
#pragma unroll
  for (int q = 0; q < 4; ++q)
    *reinterpret_cast<float4*>(&h[q * 4]) =
        *reinterpret_cast<const float4*>(hbuf + hb + q * 4);
#pragma unroll 2
  for (int t = 0; t < CL; ++t) {
    float dtv = dtp[0];
    float xav = xap[0];
    float zv = zp[0];
    float bB[16], cC[16];
#pragma unroll
    for (int q = 0; q < 4; ++q) {
      *reinterpret_cast<float4*>(&bB[q * 4]) =
          *reinterpret_cast<const float4*>(bcp + q * 4);
      *reinterpret_cast<float4*>(&cC[q * 4]) =
          *reinterpret_cast<const float4*>(bcp + 16 + q * 4);
    }
    float e1 = __expf(-dtv);
    float w = e1;
    float y = 0.0f;
#pragma unroll
    for (int n = 0; n < 16; ++n) {
      h[n] = fmaf(w, h[n], xav * bB[n]);
      w *= e1;
      y = fmaf(h[n], cC[n], y);
    }
    float sz = zv / (1.0f + __expf(-zv));
    float g = y * sz;
    u16 gh = f2bf(g);
    ghp[0] = gh;
    glp[0] = f2bf(g - bf2f(gh));
    dtp += INNER;
    xap += INNER;
    bcp += 32;
    zp += XZW;
    ghp += INNER;
    glp += INNER;
  }
}

extern "C" void kernel_launch(void* const* d_in, const int* in_sizes, int n_in,
                              void* d_out, int out_size, void* d_ws, size_t ws_size,
                              hipStream_t stream) {
  const float* x      = (const float*)d_in[0];
  const float* norm_w = (const float*)d_in[1];
  const float* norm_b = (const float*)d_in[2];
  const float* in_w   = (const float*)d_in[3];
  const float* in_b   = (const float*)d_in[4];
  const float* conv_w = (const float*)d_in[5];
  const float* conv_b = (const float*)d_in[6];
  const float* bc_w   = (const float*)d_in[7];
  const float* bc_b   = (const float*)d_in[8];
  const float* dtr_w  = (const float*)d_in[9];
  const float* dtr_b  = (const float*)d_in[10];
  const float* dt_w   = (const float*)d_in[11];
  const float* dt_b   = (const float*)d_in[12];
  const float* out_w  = (const float*)d_in[13];
  const float* out_b  = (const float*)d_in[14];

  float* ws = (float*)d_ws;
  float* xz     = ws;                   // 8,388,608
  float* xa     = ws + 8388608;         // 4,194,304
  float* bcd    = ws + 12582912;        // 196,608
  float* dt     = ws + 12779520;        // 4,194,304
  float* dtm    = ws + 16973824;        // 2,048
  float* scanBC = ws + 16975872;        // 65,536
  // region R @ 17,041,408 (6,291,456 floats), time-multiplexed:
  u16* a1hi   = (u16*)(ws + 17041408);  // 2048*1024 u16
  u16* a1lo   = (u16*)(ws + 18089984);
  u16* b1thi  = (u16*)(ws + 19138560);  // 4096*1024 u16
  u16* b1tlo  = (u16*)(ws + 21235712);
  u16* xahi   = (u16*)(ws + 17041408);  // 2048*2048 u16
  u16* xalo   = (u16*)(ws + 19138560);
  u16* bcdThi = (u16*)(ws + 21235712);  // 96*2048 u16
  u16* bcdTlo = (u16*)(ws + 21334016);
  u16* g3hi   = (u16*)(ws + 17041408);  // 2048*2048 u16
  u16* g3lo   = (u16*)(ws + 19138560);
  u16* b3thi  = (u16*)(ws + 21235712);  // 1024*2048 u16
  u16* b3tlo  = (u16*)(ws + 22284288);
  float* Abuf = ws + 23332864;          // NC*65,536
  const int NC = 64, CL = SEQ / NC;
  float* hbuf = Abuf + (size_t)NC * 65536;  // end: 31,721,472 floats = 126.9 MB

  ln_kernel<<<ROWS, 256, 0, stream>>>(x, norm_w, norm_b, a1hi, a1lo);
  cvt_t_kernel<<<dim3(XZW / 32, H / 32), 256, 0, stream>>>(in_w, b1thi, b1tlo, H, XZW);
  gemm_mfma<128, false><<<dim3(XZW / 128, ROWS / 128, 1), 256, 0, stream>>>(
      a1hi, a1lo, b1thi, b1tlo, in_b, xz, XZW, H, H);
  conv_kernel<<<ROWS, 256, 0, stream>>>(xz, conv_w, conv_b, xa, xahi, xalo);
  // weights -> bcdT (bc rows 0..31, dtr rows 32..95)
  cvt_t_kernel<<<dim3(1, INNER / 32), 256, 0, stream>>>(bc_w, bcdThi, bcdTlo,
                                                        INNER, 32);
  cvt_t_kernel<<<dim3(2, INNER / 32), 256, 0, stream>>>(
      dtr_w, bcdThi + 32 * 2048, bcdTlo + 32 * 2048, INNER, 64);
  bcd_init_kernel<<<ROWS * 96 / 256, 256, 0, stream>>>(bc_b, dtr_b, bcd);
  // bcdtr: N=96 GEMM, split-K=16 (grid 256 blocks), atomic accumulate into bcd
  gemm_mfma<96, true><<<dim3(1, ROWS / 128, 16), 256, 0, stream>>>(
      xahi, xalo, bcdThi, bcdTlo, bc_b, bcd, 96, INNER, INNER / 16);
  dtsp_kernel<<<ROWS / 8, 256, 0, stream>>>(bcd, dt_w, dt_b, dt, dtm, scanBC);
  cvt_t_kernel<<<dim3(H / 32, INNER / 32), 256, 0, stream>>>(out_w, b3thi, b3tlo,
                                                             INNER, H);
  scan1_kernel<<<2 * 32 * (NC / 4), 256, 0, stream>>>(dt, xa, scanBC, Abuf, hbuf,
                                                      NC, CL);
  scan2_kernel<<<256, 256, 0, stream>>>(Abuf, hbuf, NC);
  scan3_kernel<<<2 * 32 * (NC / 4), 256, 0, stream>>>(dt, xa, scanBC, xz, hbuf,
                                                      g3hi, g3lo, NC, CL);
  // GEMM3: split-K=2 (grid 512 = 2 blocks/CU), atomic accumulate into bias-inited out
  out_init_kernel<<<ROWS * H / 256, 256, 0, stream>>>(out_b, (float*)d_out);
  gemm_mfma<64, true><<<dim3(H / 64, ROWS / 128, 2), 256, 0, stream>>>(
      g3hi, g3lo, b3thi, b3tlo, out_b, (float*)d_out, H, INNER, INNER / 2);
}